// Round 2
// baseline (153.677 us; speedup 1.0000x reference)
//
#include <hip/hip_runtime.h>
#include <hip/hip_bf16.h>

#define Bn 4
#define Sn 2048
#define Hn 768
#define NHn 12
#define Mn (Bn*Sn)
#define QKVN 2304

typedef unsigned short u16;
typedef unsigned int u32;
typedef __attribute__((ext_vector_type(8))) short short8;
typedef __attribute__((ext_vector_type(4))) float f32x4;

typedef __attribute__((address_space(1))) const u32 g_u32;
typedef __attribute__((address_space(3))) u32 l_u32;

__device__ __forceinline__ void gll16(const void* g, void* l) {
    __builtin_amdgcn_global_load_lds((g_u32*)g, (l_u32*)l, 16, 0, 0);
}

__device__ __forceinline__ u16 f2bf(float f) {
    u32 x = __float_as_uint(f);
    x += 0x7fffu + ((x >> 16) & 1u);   // round-to-nearest-even
    return (u16)(x >> 16);
}
__device__ __forceinline__ float bf2f(u16 u) {
    return __uint_as_float(((u32)u) << 16);
}

// ---------------- fused fp32 -> bf16 casts (hs, Wqkv, Wo in one launch) ----
__global__ __launch_bounds__(256) void cast3_k(const float* __restrict__ hs,
                                               const float* __restrict__ wqkv,
                                               const float* __restrict__ wo,
                                               u16* __restrict__ hs_b,
                                               u16* __restrict__ wqkv_b,
                                               u16* __restrict__ wo_b) {
    int i = blockIdx.x * 256 + threadIdx.x;
    const float* s; u16* d; int off;
    if (i < 1572864)      { s = hs;   d = hs_b;   off = i; }
    else if (i < 2015232) { s = wqkv; d = wqkv_b; off = i - 1572864; }
    else if (i < 2162688) { s = wo;   d = wo_b;   off = i - 2015232; }
    else return;
    float4 v = ((const float4*)s)[off];
    ushort4 o;
    o.x = f2bf(v.x); o.y = f2bf(v.y); o.z = f2bf(v.z); o.w = f2bf(v.w);
    ((ushort4*)d)[off] = o;
}

// ---------------- bf16 GEMM: C[M][N] = A[M][K] * B[N][K]^T ----------------
// 128x128 tile, BK=64, 4 waves (2x2), each wave 64x64 (4x4 frags of 16x16).
// LDS row stride 128B = 8x16B granules; XOR swizzle slot^(row&7) gives exact
// 2-way bank aliasing (free) on ds_read_b128. global_load_lds dest is linear,
// so the inverse swizzle is applied to the global source column.
// ROPE: fuse rotary embedding into the epilogue for cols < 1536 (q,k).
template <typename OUT, bool ROPE>
__global__ __launch_bounds__(256) void gemm_bt(const u16* __restrict__ A,
                                               const u16* __restrict__ Bw,
                                               OUT* __restrict__ C,
                                               const int* __restrict__ pos_ids,
                                               int N, int K) {
    __shared__ __align__(16) u16 As[128 * 64];
    __shared__ __align__(16) u16 Bs[128 * 64];
    const int t = threadIdx.x;
    const int wid = t >> 6, lane = t & 63;
    const int wr = wid >> 1, wc = wid & 1;
    const long m0 = (long)blockIdx.x * 128;
    const long n0 = (long)blockIdx.y * 128;
    const int lr = lane & 15, g = lane >> 4;

    f32x4 acc[4][4] = {};

    for (int kt = 0; kt < K; kt += 64) {
        #pragma unroll
        for (int ss = 0; ss < 4; ++ss) {
            int s = t + ss * 256;          // 0..1023
            int row = s >> 3, gg = s & 7;
            int col8 = (gg ^ (row & 7)) * 8;   // inverse-swizzled source col
            gll16(A + (m0 + row) * K + kt + col8, (char*)As + s * 16);
            gll16(Bw + (n0 + row) * K + kt + col8, (char*)Bs + s * 16);
        }
        __syncthreads();
        #pragma unroll
        for (int kk2 = 0; kk2 < 2; ++kk2) {
            short8 af[4], bfr[4];
            #pragma unroll
            for (int mt = 0; mt < 4; ++mt) {
                int row = wr * 64 + mt * 16 + lr;
                int slot = kk2 * 4 + g;
                af[mt] = *(const short8*)((const char*)As + row * 128 +
                                          ((slot ^ (row & 7)) << 4));
            }
            #pragma unroll
            for (int nt = 0; nt < 4; ++nt) {
                int row = wc * 64 + nt * 16 + lr;
                int slot = kk2 * 4 + g;
                bfr[nt] = *(const short8*)((const char*)Bs + row * 128 +
                                           ((slot ^ (row & 7)) << 4));
            }
            #pragma unroll
            for (int mt = 0; mt < 4; ++mt)
                #pragma unroll
                for (int nt = 0; nt < 4; ++nt)
                    acc[mt][nt] = __builtin_amdgcn_mfma_f32_16x16x32_bf16(
                        af[mt], bfr[nt], acc[mt][nt], 0, 0, 0);
        }
        __syncthreads();
    }

    // ---- epilogue: optional fused RoPE (wave-uniform: one head per wave) ----
    if (ROPE && (n0 + wc * 64) < 1536) {
        float invf0 = exp2f((float)lr * -0.4152410119f);          // d2 = lr
        float invf1 = exp2f((float)(lr + 16) * -0.4152410119f);   // d2 = lr+16
        #pragma unroll
        for (int mt = 0; mt < 4; ++mt)
            #pragma unroll
            for (int r = 0; r < 4; ++r) {
                long row = m0 + wr * 64 + mt * 16 + g * 4 + r;
                float pos = (float)pos_ids[row];
                #pragma unroll
                for (int ntp = 0; ntp < 2; ++ntp) {
                    float fr = pos * (ntp ? invf1 : invf0);
                    float sn, cs;
                    sincosf(fr, &sn, &cs);
                    float x1 = acc[mt][ntp][r], x2 = acc[mt][ntp + 2][r];
                    acc[mt][ntp][r]     = x1 * cs - x2 * sn;
                    acc[mt][ntp + 2][r] = x2 * cs + x1 * sn;
                }
            }
    }

    #pragma unroll
    for (int mt = 0; mt < 4; ++mt)
        #pragma unroll
        for (int nt = 0; nt < 4; ++nt)
            #pragma unroll
            for (int r = 0; r < 4; ++r) {
                long row = m0 + wr * 64 + mt * 16 + g * 4 + r;
                long col = n0 + wc * 64 + nt * 16 + lr;
                float v = acc[mt][nt][r];
                if constexpr (sizeof(OUT) == 2) C[row * N + col] = (OUT)f2bf(v);
                else                            C[row * N + col] = v;
            }
}

// ---------------- windowed attention ----------------
// block = (q-tile of 64, b*NH+h), 4 waves, each wave owns 16 q-rows.
// KV range = [q0-64, q0+127] (192 keys) covers window +-64 in one pass.
__global__ __launch_bounds__(256) void attn_k(const u16* __restrict__ qkv,
                                              u16* __restrict__ outb) {
    const int qt = blockIdx.x, bh = blockIdx.y;
    const int b = bh / NHn, h = bh % NHn;
    const int q0 = qt * 64, kv0 = q0 - 64;
    const int t = threadIdx.x, wid = t >> 6, lane = t & 63;
    const int lr = lane & 15, g = lane >> 4;

    __shared__ __align__(16) char smem[58368];
    u16* Qs = (u16*)smem;                // [64][64] swizzled, 8192 B
    u16* Ks = (u16*)(smem + 8192);       // [192][64] swizzled, 24576 B
    u16* Vt = (u16*)(smem + 32768);      // [64][200] transposed V, 25600 B
    // P region reuses [0, 25600) after QK^T (Qs+Ks dead by then)

    const size_t rowbase = (size_t)b * Sn;

    // stage Q (global_load_lds, linear LDS + inverse-swizzled source)
    #pragma unroll
    for (int ss = 0; ss < 2; ++ss) {
        int s = t + ss * 256;
        int row = s >> 3, gg = s & 7;
        int col8 = (gg ^ (row & 7)) * 8;
        gll16(qkv + (rowbase + q0 + row) * QKVN + h * 64 + col8, (char*)Qs + s * 16);
    }
    // stage K (rows clamped; mask covers OOB/garbage)
    #pragma unroll
    for (int ss = 0; ss < 6; ++ss) {
        int s = t + ss * 256;
        int row = s >> 3, gg = s & 7;
        int kk = kv0 + row;
        kk = kk < 0 ? 0 : (kk > Sn - 1 ? Sn - 1 : kk);
        int col8 = (gg ^ (row & 7)) * 8;
        gll16(qkv + (rowbase + kk) * QKVN + 768 + h * 64 + col8, (char*)Ks + s * 16);
    }
    // stage V transposed (reg-staged: coalesced 16B global read, 2B LDS scatter)
    #pragma unroll
    for (int ss = 0; ss < 6; ++ss) {
        int s = t + ss * 256;
        int krow = s >> 3, gg = s & 7;
        int kk = kv0 + krow;
        kk = kk < 0 ? 0 : (kk > Sn - 1 ? Sn - 1 : kk);
        short8 v = *(const short8*)(qkv + (rowbase + kk) * QKVN + 1536 + h * 64 + gg * 8);
        #pragma unroll
        for (int j = 0; j < 8; ++j) Vt[(gg * 8 + j) * 200 + krow] = (u16)v[j];
    }
    __syncthreads();

    // QK^T: 12 key-tiles x 2 d-halves = 24 MFMA per wave
    f32x4 sacc[12] = {};
    #pragma unroll
    for (int kk2 = 0; kk2 < 2; ++kk2) {
        int qrow = wid * 16 + lr;
        int slot = kk2 * 4 + g;
        short8 qf = *(const short8*)((const char*)Qs + qrow * 128 + ((slot ^ (qrow & 7)) << 4));
        #pragma unroll
        for (int tl = 0; tl < 12; ++tl) {
            int krow = tl * 16 + lr;
            short8 kf = *(const short8*)((const char*)Ks + krow * 128 + ((slot ^ (krow & 7)) << 4));
            sacc[tl] = __builtin_amdgcn_mfma_f32_16x16x32_bf16(qf, kf, sacc[tl], 0, 0, 0);
        }
    }

    // mask + softmax (row lives in a 16-lane group; width-16 shfl_xor reduce)
    float p[12][4];
    float lsum[4];
    #pragma unroll
    for (int r = 0; r < 4; ++r) {
        int qq = q0 + wid * 16 + g * 4 + r;
        float mx = -3.0e38f;
        #pragma unroll
        for (int tl = 0; tl < 12; ++tl) {
            int kq = kv0 + tl * 16 + lr;
            float sc = sacc[tl][r] * 0.125f;
            int dqk = qq - kq;
            bool valid = (kq >= 0) && (kq < Sn) && (dqk <= 64) && (dqk >= -64);
            sc = valid ? sc : -3.0e38f;
            p[tl][r] = sc;
            mx = fmaxf(mx, sc);
        }
        #pragma unroll
        for (int mk = 1; mk < 16; mk <<= 1) mx = fmaxf(mx, __shfl_xor(mx, mk, 16));
        float sum = 0.f;
        #pragma unroll
        for (int tl = 0; tl < 12; ++tl) {
            float e = __expf(p[tl][r] - mx);
            p[tl][r] = e;
            sum += e;
        }
        #pragma unroll
        for (int mk = 1; mk < 16; mk <<= 1) sum += __shfl_xor(sum, mk, 16);
        lsum[r] = sum;
    }

    __syncthreads();   // all waves done reading Qs/Ks before P overwrite

    // write P (bf16) to per-wave chunk, padded stride 200 elems (conflict-free)
    u16* Pw = (u16*)(smem + wid * 6400);
    #pragma unroll
    for (int tl = 0; tl < 12; ++tl)
        #pragma unroll
        for (int r = 0; r < 4; ++r)
            Pw[(g * 4 + r) * 200 + tl * 16 + lr] = f2bf(p[tl][r]);

    // PV: O(16x64) = P(16x192) * V(192x64); 6 k-steps x 4 d-tiles = 24 MFMA
    f32x4 oacc[4] = {};
    #pragma unroll
    for (int ks = 0; ks < 6; ++ks) {
        short8 pf = *(const short8*)((const char*)Pw + lr * 400 + (ks * 32 + g * 8) * 2);
        #pragma unroll
        for (int dt = 0; dt < 4; ++dt) {
            short8 vf = *(const short8*)((const char*)Vt + (dt * 16 + lr) * 400 + (ks * 32 + g * 8) * 2);
            oacc[dt] = __builtin_amdgcn_mfma_f32_16x16x32_bf16(pf, vf, oacc[dt], 0, 0, 0);
        }
    }

    // epilogue: divide by row sum, write bf16 [B*S][768] (head-major cols)
    #pragma unroll
    for (int dt = 0; dt < 4; ++dt)
        #pragma unroll
        for (int r = 0; r < 4; ++r) {
            int row = q0 + wid * 16 + g * 4 + r;
            float v = oacc[dt][r] / lsum[r];
            outb[(rowbase + row) * Hn + h * 64 + dt * 16 + lr] = f2bf(v);
        }
}

extern "C" void kernel_launch(void* const* d_in, const int* in_sizes, int n_in,
                              void* d_out, int out_size, void* d_ws, size_t ws_size,
                              hipStream_t stream) {
    const float* hs   = (const float*)d_in[0];
    const int*   pos  = (const int*)d_in[1];
    const float* wqkv = (const float*)d_in[2];
    const float* wo   = (const float*)d_in[3];
    float* out = (float*)d_out;
    char* ws = (char*)d_ws;

    // workspace layout (bytes)
    u16* hs_b   = (u16*)(ws);              // 8192*768*2   = 12,582,912
    u16* wqkv_b = (u16*)(ws + 12582912);   // 2304*768*2   =  3,538,944
    u16* wo_b   = (u16*)(ws + 16121856);   // 768*768*2    =  1,179,648
    u16* qkv    = (u16*)(ws + 17301504);   // 8192*2304*2  = 37,748,736
    u16* attn   = (u16*)(ws + 55050240);   // 8192*768*2   = 12,582,912  (end 67,633,152)

    cast3_k<<<8448, 256, 0, stream>>>(hs, wqkv, wo, hs_b, wqkv_b, wo_b);

    // qkv[M][2304] = hs[M][768] @ Wqkv[2304][768]^T, RoPE fused on q,k cols
    gemm_bt<u16, true><<<dim3(64, 18), 256, 0, stream>>>(hs_b, wqkv_b, qkv, pos, 2304, 768);

    attn_k<<<dim3(32, 48), 256, 0, stream>>>(qkv, attn);

    // out[M][768] = attn[M][768] @ Wo[768][768]^T  (fp32 output)
    gemm_bt<float, false><<<dim3(64, 6), 256, 0, stream>>>(attn, wo_b, out, nullptr, 768, 768);
}

// Round 3
// 98.876 us; speedup vs baseline: 1.5542x; 1.5542x over previous
//
#include <hip/hip_runtime.h>
#include <hip/hip_bf16.h>

#define Bn 4
#define Sn 2048
#define Hn 768
#define NHn 12
#define Mn (Bn*Sn)
#define QKVN 2304

typedef unsigned short u16;
typedef unsigned int u32;
typedef __attribute__((ext_vector_type(8))) short short8;
typedef __attribute__((ext_vector_type(4))) float f32x4;

typedef __attribute__((address_space(1))) const u32 g_u32;
typedef __attribute__((address_space(3))) u32 l_u32;

__device__ __forceinline__ void gll16(const void* g, void* l) {
    __builtin_amdgcn_global_load_lds((g_u32*)g, (l_u32*)l, 16, 0, 0);
}

__device__ __forceinline__ u16 f2bf(float f) {
    u32 x = __float_as_uint(f);
    x += 0x7fffu + ((x >> 16) & 1u);   // round-to-nearest-even
    return (u16)(x >> 16);
}
__device__ __forceinline__ float bf2f(u16 u) {
    return __uint_as_float(((u32)u) << 16);
}

// ---------------- fused fp32 -> bf16 casts (hs, Wqkv, Wo in one launch) ----
__global__ __launch_bounds__(256) void cast3_k(const float* __restrict__ hs,
                                               const float* __restrict__ wqkv,
                                               const float* __restrict__ wo,
                                               u16* __restrict__ hs_b,
                                               u16* __restrict__ wqkv_b,
                                               u16* __restrict__ wo_b) {
    int i = blockIdx.x * 256 + threadIdx.x;
    const float* s; u16* d; int off;
    if (i < 1572864)      { s = hs;   d = hs_b;   off = i; }
    else if (i < 2015232) { s = wqkv; d = wqkv_b; off = i - 1572864; }
    else if (i < 2162688) { s = wo;   d = wo_b;   off = i - 2015232; }
    else return;
    float4 v = ((const float4*)s)[off];
    ushort4 o;
    o.x = f2bf(v.x); o.y = f2bf(v.y); o.z = f2bf(v.z); o.w = f2bf(v.w);
    ((ushort4*)d)[off] = o;
}

// ---------------- RoPE cos/sin table: tab[row][d2], d2 in [0,32) ----------
__global__ __launch_bounds__(256) void tab_k(const int* __restrict__ pos_ids,
                                             float2* __restrict__ tab) {
    int idx = blockIdx.x * 256 + threadIdx.x;    // Mn*32 exact
    int d2 = idx & 31, row = idx >> 5;
    float invf = exp2f((float)d2 * -0.4152410119f);   // 10000^(-d2/32)
    float fr = (float)pos_ids[row] * invf;
    float sn, cs;
    sincosf(fr, &sn, &cs);
    tab[idx] = make_float2(cs, sn);
}

// ---------------- bf16 GEMM: C[M][N] = A[M][K] * B[N][K]^T ----------------
// BMxBN tile, BK=64, 4 waves (2x2), per-wave (BM/2)x(BN/2) of 16x16 frags.
// LDS row stride 128B = 8x16B granules; XOR swizzle slot^(row&7) -> exact
// 2-way bank aliasing (free) on ds_read_b128. global_load_lds dest is linear,
// so the inverse swizzle is applied to the global source column.
// ROPE: fused rotary via precomputed cos/sin table (no transcendentals).
template <int BM, int BN, typename OUT, bool ROPE>
__global__ __launch_bounds__(256, 4) void gemm_bt(const u16* __restrict__ A,
                                                  const u16* __restrict__ Bw,
                                                  OUT* __restrict__ C,
                                                  const float2* __restrict__ tab,
                                                  int N, int K) {
    constexpr int WM = BM / 2, WN = BN / 2;
    constexpr int MR = WM / 16, NR = WN / 16;
    static_assert(!ROPE || NR == 4, "ROPE fusion assumes wave spans one 64-head");
    __shared__ __align__(16) u16 As[BM * 64];
    __shared__ __align__(16) u16 Bs[BN * 64];
    const int t = threadIdx.x;
    const int wid = t >> 6, lane = t & 63;
    const int wr = wid >> 1, wc = wid & 1;
    const long m0 = (long)blockIdx.x * BM;
    const long n0 = (long)blockIdx.y * BN;
    const int lr = lane & 15, g = lane >> 4;

    f32x4 acc[MR][NR] = {};

    for (int kt = 0; kt < K; kt += 64) {
        #pragma unroll
        for (int ss = 0; ss < BM / 32; ++ss) {
            int s = t + ss * 256;
            int row = s >> 3, gg = s & 7;
            int col8 = (gg ^ (row & 7)) * 8;   // inverse-swizzled source col
            gll16(A + (m0 + row) * K + kt + col8, (char*)As + s * 16);
        }
        #pragma unroll
        for (int ss = 0; ss < BN / 32; ++ss) {
            int s = t + ss * 256;
            int row = s >> 3, gg = s & 7;
            int col8 = (gg ^ (row & 7)) * 8;
            gll16(Bw + (n0 + row) * K + kt + col8, (char*)Bs + s * 16);
        }
        __syncthreads();
        #pragma unroll
        for (int kk2 = 0; kk2 < 2; ++kk2) {
            const int slot = kk2 * 4 + g;
            short8 bfr[NR];
            #pragma unroll
            for (int nt = 0; nt < NR; ++nt) {
                int row = wc * WN + nt * 16 + lr;
                bfr[nt] = *(const short8*)((const char*)Bs + row * 128 +
                                           ((slot ^ (row & 7)) << 4));
            }
            #pragma unroll
            for (int mt = 0; mt < MR; ++mt) {
                int row = wr * WM + mt * 16 + lr;
                short8 af = *(const short8*)((const char*)As + row * 128 +
                                             ((slot ^ (row & 7)) << 4));
                #pragma unroll
                for (int nt = 0; nt < NR; ++nt)
                    acc[mt][nt] = __builtin_amdgcn_mfma_f32_16x16x32_bf16(
                        af, bfr[nt], acc[mt][nt], 0, 0, 0);
            }
        }
        __syncthreads();
    }

    // ---- epilogue: fused RoPE via table (wave spans exactly one head) ----
    if constexpr (ROPE) {
        if ((n0 + wc * WN) < 1536) {
            #pragma unroll
            for (int mt = 0; mt < MR; ++mt)
                #pragma unroll
                for (int r = 0; r < 4; ++r) {
                    long row = m0 + wr * WM + mt * 16 + g * 4 + r;
                    const float2* tr = tab + row * 32;
                    #pragma unroll
                    for (int ntp = 0; ntp < 2; ++ntp) {
                        float2 cssn = tr[ntp * 16 + lr];
                        float x1 = acc[mt][ntp][r], x2 = acc[mt][ntp + 2][r];
                        acc[mt][ntp][r]     = x1 * cssn.x - x2 * cssn.y;
                        acc[mt][ntp + 2][r] = x2 * cssn.x + x1 * cssn.y;
                    }
                }
        }
    }

    #pragma unroll
    for (int mt = 0; mt < MR; ++mt)
        #pragma unroll
        for (int nt = 0; nt < NR; ++nt)
            #pragma unroll
            for (int r = 0; r < 4; ++r) {
                long row = m0 + wr * WM + mt * 16 + g * 4 + r;
                long col = n0 + wc * WN + nt * 16 + lr;
                float v = acc[mt][nt][r];
                if constexpr (sizeof(OUT) == 2) C[row * N + col] = (OUT)f2bf(v);
                else                            C[row * N + col] = v;
            }
}

// ---------------- windowed attention ----------------
// block = (q-tile of 64, b*NH+h), 4 waves, each wave owns 16 q-rows.
// KV range = [q0-64, q0+127] (192 keys) covers window +-64 in one pass.
__global__ __launch_bounds__(256) void attn_k(const u16* __restrict__ qkv,
                                              u16* __restrict__ outb) {
    const int qt = blockIdx.x, bh = blockIdx.y;
    const int b = bh / NHn, h = bh % NHn;
    const int q0 = qt * 64, kv0 = q0 - 64;
    const int t = threadIdx.x, wid = t >> 6, lane = t & 63;
    const int lr = lane & 15, g = lane >> 4;

    __shared__ __align__(16) char smem[58368];
    u16* Qs = (u16*)smem;                // [64][64] swizzled, 8192 B
    u16* Ks = (u16*)(smem + 8192);       // [192][64] swizzled, 24576 B
    u16* Vt = (u16*)(smem + 32768);      // [64][200] transposed V, 25600 B
    // P region reuses [0, 25600) after QK^T (Qs+Ks dead by then)

    const size_t rowbase = (size_t)b * Sn;

    // stage Q (global_load_lds, linear LDS + inverse-swizzled source)
    #pragma unroll
    for (int ss = 0; ss < 2; ++ss) {
        int s = t + ss * 256;
        int row = s >> 3, gg = s & 7;
        int col8 = (gg ^ (row & 7)) * 8;
        gll16(qkv + (rowbase + q0 + row) * QKVN + h * 64 + col8, (char*)Qs + s * 16);
    }
    // stage K (rows clamped; mask covers OOB/garbage)
    #pragma unroll
    for (int ss = 0; ss < 6; ++ss) {
        int s = t + ss * 256;
        int row = s >> 3, gg = s & 7;
        int kk = kv0 + row;
        kk = kk < 0 ? 0 : (kk > Sn - 1 ? Sn - 1 : kk);
        int col8 = (gg ^ (row & 7)) * 8;
        gll16(qkv + (rowbase + kk) * QKVN + 768 + h * 64 + col8, (char*)Ks + s * 16);
    }
    // stage V transposed (reg-staged: coalesced 16B global read, 2B LDS scatter)
    #pragma unroll
    for (int ss = 0; ss < 6; ++ss) {
        int s = t + ss * 256;
        int krow = s >> 3, gg = s & 7;
        int kk = kv0 + krow;
        kk = kk < 0 ? 0 : (kk > Sn - 1 ? Sn - 1 : kk);
        short8 v = *(const short8*)(qkv + (rowbase + kk) * QKVN + 1536 + h * 64 + gg * 8);
        #pragma unroll
        for (int j = 0; j < 8; ++j) Vt[(gg * 8 + j) * 200 + krow] = (u16)v[j];
    }
    __syncthreads();

    // QK^T: 12 key-tiles x 2 d-halves = 24 MFMA per wave
    f32x4 sacc[12] = {};
    #pragma unroll
    for (int kk2 = 0; kk2 < 2; ++kk2) {
        int qrow = wid * 16 + lr;
        int slot = kk2 * 4 + g;
        short8 qf = *(const short8*)((const char*)Qs + qrow * 128 + ((slot ^ (qrow & 7)) << 4));
        #pragma unroll
        for (int tl = 0; tl < 12; ++tl) {
            int krow = tl * 16 + lr;
            short8 kf = *(const short8*)((const char*)Ks + krow * 128 + ((slot ^ (krow & 7)) << 4));
            sacc[tl] = __builtin_amdgcn_mfma_f32_16x16x32_bf16(qf, kf, sacc[tl], 0, 0, 0);
        }
    }

    // mask + softmax (row lives in a 16-lane group; width-16 shfl_xor reduce)
    float p[12][4];
    float lsum[4];
    #pragma unroll
    for (int r = 0; r < 4; ++r) {
        int qq = q0 + wid * 16 + g * 4 + r;
        float mx = -3.0e38f;
        #pragma unroll
        for (int tl = 0; tl < 12; ++tl) {
            int kq = kv0 + tl * 16 + lr;
            float sc = sacc[tl][r] * 0.125f;
            int dqk = qq - kq;
            bool valid = (kq >= 0) && (kq < Sn) && (dqk <= 64) && (dqk >= -64);
            sc = valid ? sc : -3.0e38f;
            p[tl][r] = sc;
            mx = fmaxf(mx, sc);
        }
        #pragma unroll
        for (int mk = 1; mk < 16; mk <<= 1) mx = fmaxf(mx, __shfl_xor(mx, mk, 16));
        float sum = 0.f;
        #pragma unroll
        for (int tl = 0; tl < 12; ++tl) {
            float e = __expf(p[tl][r] - mx);
            p[tl][r] = e;
            sum += e;
        }
        #pragma unroll
        for (int mk = 1; mk < 16; mk <<= 1) sum += __shfl_xor(sum, mk, 16);
        lsum[r] = sum;
    }

    __syncthreads();   // all waves done reading Qs/Ks before P overwrite

    // write P (bf16) to per-wave chunk, padded stride 200 elems (conflict-free)
    u16* Pw = (u16*)(smem + wid * 6400);
    #pragma unroll
    for (int tl = 0; tl < 12; ++tl)
        #pragma unroll
        for (int r = 0; r < 4; ++r)
            Pw[(g * 4 + r) * 200 + tl * 16 + lr] = f2bf(p[tl][r]);

    // PV: O(16x64) = P(16x192) * V(192x64); 6 k-steps x 4 d-tiles = 24 MFMA
    f32x4 oacc[4] = {};
    #pragma unroll
    for (int ks = 0; ks < 6; ++ks) {
        short8 pf = *(const short8*)((const char*)Pw + lr * 400 + (ks * 32 + g * 8) * 2);
        #pragma unroll
        for (int dt = 0; dt < 4; ++dt) {
            short8 vf = *(const short8*)((const char*)Vt + (dt * 16 + lr) * 400 + (ks * 32 + g * 8) * 2);
            oacc[dt] = __builtin_amdgcn_mfma_f32_16x16x32_bf16(pf, vf, oacc[dt], 0, 0, 0);
        }
    }

    // epilogue: divide by row sum, write bf16 [B*S][768] (head-major cols)
    #pragma unroll
    for (int dt = 0; dt < 4; ++dt)
        #pragma unroll
        for (int r = 0; r < 4; ++r) {
            int row = q0 + wid * 16 + g * 4 + r;
            float v = oacc[dt][r] / lsum[r];
            outb[(rowbase + row) * Hn + h * 64 + dt * 16 + lr] = f2bf(v);
        }
}

extern "C" void kernel_launch(void* const* d_in, const int* in_sizes, int n_in,
                              void* d_out, int out_size, void* d_ws, size_t ws_size,
                              hipStream_t stream) {
    const float* hs   = (const float*)d_in[0];
    const int*   pos  = (const int*)d_in[1];
    const float* wqkv = (const float*)d_in[2];
    const float* wo   = (const float*)d_in[3];
    float* out = (float*)d_out;
    char* ws = (char*)d_ws;

    // workspace layout (bytes)
    u16* hs_b   = (u16*)(ws);              // 8192*768*2   = 12,582,912
    u16* wqkv_b = (u16*)(ws + 12582912);   // 2304*768*2   =  3,538,944
    u16* wo_b   = (u16*)(ws + 16121856);   // 768*768*2    =  1,179,648
    u16* qkv    = (u16*)(ws + 17301504);   // 8192*2304*2  = 37,748,736
    u16* attn   = (u16*)(ws + 55050240);   // 8192*768*2   = 12,582,912  (end 67,633,152)
    // rope table (2 MB) overlaps the attn buffer: tab is consumed by gemm1,
    // attn_k (which overwrites the region) runs strictly after gemm1.
    float2* tab = (float2*)(ws + 55050240);

    cast3_k<<<8448, 256, 0, stream>>>(hs, wqkv, wo, hs_b, wqkv_b, wo_b);
    tab_k<<<1024, 256, 0, stream>>>(pos, tab);

    // qkv[M][2304] = hs[M][768] @ Wqkv[2304][768]^T, RoPE fused on q,k cols
    gemm_bt<128, 128, u16, true><<<dim3(64, 18), 256, 0, stream>>>(
        hs_b, wqkv_b, qkv, tab, 2304, 768);

    attn_k<<<dim3(32, 48), 256, 0, stream>>>(qkv, attn);

    // out[M][768] = attn[M][768] @ Wo[768][768]^T  (fp32 output)
    gemm_bt<128, 64, float, false><<<dim3(64, 12), 256, 0, stream>>>(
        attn, wo_b, out, nullptr, 768, 768);
}